// Round 8
// baseline (112.036 us; speedup 1.0000x reference)
//
#include <hip/hip_runtime.h>

// Viterbi trellis quantizer: S=1024, K=2 (4 preds), CHUNK=4, T=64 steps,
// B=4096 chains. ONE wave per chain (64-thread block): no barriers, LDS ops
// in-order within the wave. The entire 63-step forward recursion is ONE
// inline-asm block with explicit physical registers (v22..v127 clobbered):
// R1-R7 showed the allocator pins arch VGPRs at the 32/64 tier and shuttles
// the 80-reg codebook through AGPRs/scratch (~2x instruction bloat,
// 58-65 us across five different structures). Explicit asm regs make that
// impossible. v_pk_fma_f32 packs 2 states per FMA op.
//
// Register map: v22 tile-addr, v23 J-addr, v24..v103 codebook (8 blocks of
// 10: (P,j) -> base 24+40P+10j: ax,ay,az,aw,h pairs over states
// s = 4L+2P+{0,1}+256j), v104..111 xt broadcast pairs, v112..115 m_j,
// v116..119 best (M write quad), v120..123 argmax idx, v124..125 ctmp,
// v126 M-read addr, v127 M-write addr. s20 loop counter.
//
// beta-form (validated R4-R7, absmax 0): cand_{c,j} = h + cb.x*x+..+cb.w*w
// + m_j (fma chain), M_new[4L+c] = max_j cand, first-max via strict-> 
// tournament; J byte per lane per step = 4 groups x 2 bits.

#define COLS      1024
#define T_STEPS   64
#define REC_SIZE  (1024 * 1024)

__global__ __launch_bounds__(64) void viterbi_q(
    const float* __restrict__ arr,
    const float* __restrict__ cbook,
    float* __restrict__ out)
{
    const int lane  = threadIdx.x;   // 0..63
    const int chain = blockIdx.x;    // 0..4095
    const int rb    = chain >> 6;    // block-row
    const int cbc   = chain & 63;    // block-col

    __shared__ __align__(16) float tile2[512];   // dup pairs: (x,x,y,y,z,z,w,w)/step
    __shared__ __align__(16) float Msh[256];     // grouped-max M (single buffer)
    __shared__ unsigned char Jsh[63 * 64];       // backpointers: 1 byte/lane/step
    __shared__ int st_lds[64];                   // traced-back states

    // ---- stage the 16x16 tile as broadcast PAIRS (for v_pk ops) ----
    {
        const int r  = lane >> 2;
        const int c4 = (lane & 3) << 2;
        float4 v = *(const float4*)(arr + (rb * 16 + r) * COLS + cbc * 16 + c4);
        *(float4*)&tile2[lane * 8]     = make_float4(v.x, v.x, v.y, v.y);
        *(float4*)&tile2[lane * 8 + 4] = make_float4(v.z, v.z, v.w, v.w);
    }

    const unsigned t_off  = (unsigned)(uintptr_t)&tile2[0];          // uniform
    const unsigned j_off  = (unsigned)(uintptr_t)&Jsh[0] + lane;
    const unsigned mr_off = (unsigned)(uintptr_t)&Msh[0] + lane * 4;
    const unsigned mw_off = (unsigned)(uintptr_t)&Msh[0] + lane * 16;
    const unsigned g_off  = (unsigned)(lane * 64);   // cbook byte offset of row 4L

    asm volatile(
        // ---- init addresses, drain C++ LDS staging ----
        "s_waitcnt lgkmcnt(0)\n"
        "v_mov_b32 v22, %[vt]\n"
        "v_mov_b32 v23, %[vj]\n"
        "v_mov_b32 v124, %[go]\n"
        // ---- load 16 codebook rows: P0 pairs (rows 4L+{0,1}+256j) -> v64..95
        "global_load_dwordx4 v[64:67], v124, %[cbp]\n"
        "global_load_dwordx4 v[68:71], v124, %[cbp] offset:16\n"
        "v_add_u32 v124, 0x1000, v124\n"
        "global_load_dwordx4 v[72:75], v124, %[cbp]\n"
        "global_load_dwordx4 v[76:79], v124, %[cbp] offset:16\n"
        "v_add_u32 v124, 0x1000, v124\n"
        "global_load_dwordx4 v[80:83], v124, %[cbp]\n"
        "global_load_dwordx4 v[84:87], v124, %[cbp] offset:16\n"
        "v_add_u32 v124, 0x1000, v124\n"
        "global_load_dwordx4 v[88:91], v124, %[cbp]\n"
        "global_load_dwordx4 v[92:95], v124, %[cbp] offset:16\n"
        // P1 pairs (rows 4L+{2,3}+256j) -> v96..127
        "v_add_u32 v124, 0xffffd020, v124\n"
        "global_load_dwordx4 v[96:99], v124, %[cbp]\n"
        "global_load_dwordx4 v[100:103], v124, %[cbp] offset:16\n"
        "v_add_u32 v124, 0x1000, v124\n"
        "global_load_dwordx4 v[104:107], v124, %[cbp]\n"
        "global_load_dwordx4 v[108:111], v124, %[cbp] offset:16\n"
        "v_add_u32 v124, 0x1000, v124\n"
        "global_load_dwordx4 v[112:115], v124, %[cbp]\n"
        "global_load_dwordx4 v[116:119], v124, %[cbp] offset:16\n"
        "v_add_u32 v124, 0x1000, v124\n"
        "global_load_dwordx4 v[120:123], v124, %[cbp]\n"
        "global_load_dwordx4 v[124:127], v124, %[cbp] offset:16\n"
        "s_waitcnt vmcnt(0)\n"
        // ---- transpose P0 blocks (b <- q0,q1): 24<-64,68  34<-72,76  44<-80,84  54<-88,92
        "v_mov_b32 v24, v64\n"  "v_mov_b32 v25, v68\n"
        "v_mov_b32 v26, v65\n"  "v_mov_b32 v27, v69\n"
        "v_mov_b32 v28, v66\n"  "v_mov_b32 v29, v70\n"
        "v_mov_b32 v30, v67\n"  "v_mov_b32 v31, v71\n"
        "v_mul_f32 v32, v64, v64\n" "v_fmac_f32 v32, v65, v65\n"
        "v_fmac_f32 v32, v66, v66\n" "v_fmac_f32 v32, v67, v67\n"
        "v_mul_f32 v32, -0.5, v32\n"
        "v_mul_f32 v33, v68, v68\n" "v_fmac_f32 v33, v69, v69\n"
        "v_fmac_f32 v33, v70, v70\n" "v_fmac_f32 v33, v71, v71\n"
        "v_mul_f32 v33, -0.5, v33\n"
        "v_mov_b32 v34, v72\n"  "v_mov_b32 v35, v76\n"
        "v_mov_b32 v36, v73\n"  "v_mov_b32 v37, v77\n"
        "v_mov_b32 v38, v74\n"  "v_mov_b32 v39, v78\n"
        "v_mov_b32 v40, v75\n"  "v_mov_b32 v41, v79\n"
        "v_mul_f32 v42, v72, v72\n" "v_fmac_f32 v42, v73, v73\n"
        "v_fmac_f32 v42, v74, v74\n" "v_fmac_f32 v42, v75, v75\n"
        "v_mul_f32 v42, -0.5, v42\n"
        "v_mul_f32 v43, v76, v76\n" "v_fmac_f32 v43, v77, v77\n"
        "v_fmac_f32 v43, v78, v78\n" "v_fmac_f32 v43, v79, v79\n"
        "v_mul_f32 v43, -0.5, v43\n"
        "v_mov_b32 v44, v80\n"  "v_mov_b32 v45, v84\n"
        "v_mov_b32 v46, v81\n"  "v_mov_b32 v47, v85\n"
        "v_mov_b32 v48, v82\n"  "v_mov_b32 v49, v86\n"
        "v_mov_b32 v50, v83\n"  "v_mov_b32 v51, v87\n"
        "v_mul_f32 v52, v80, v80\n" "v_fmac_f32 v52, v81, v81\n"
        "v_fmac_f32 v52, v82, v82\n" "v_fmac_f32 v52, v83, v83\n"
        "v_mul_f32 v52, -0.5, v52\n"
        "v_mul_f32 v53, v84, v84\n" "v_fmac_f32 v53, v85, v85\n"
        "v_fmac_f32 v53, v86, v86\n" "v_fmac_f32 v53, v87, v87\n"
        "v_mul_f32 v53, -0.5, v53\n"
        "v_mov_b32 v54, v88\n"  "v_mov_b32 v55, v92\n"
        "v_mov_b32 v56, v89\n"  "v_mov_b32 v57, v93\n"
        "v_mov_b32 v58, v90\n"  "v_mov_b32 v59, v94\n"
        "v_mov_b32 v60, v91\n"  "v_mov_b32 v61, v95\n"
        "v_mul_f32 v62, v88, v88\n" "v_fmac_f32 v62, v89, v89\n"
        "v_fmac_f32 v62, v90, v90\n" "v_fmac_f32 v62, v91, v91\n"
        "v_mul_f32 v62, -0.5, v62\n"
        "v_mul_f32 v63, v92, v92\n" "v_fmac_f32 v63, v93, v93\n"
        "v_fmac_f32 v63, v94, v94\n" "v_fmac_f32 v63, v95, v95\n"
        "v_mul_f32 v63, -0.5, v63\n"
        // ---- transpose P1 blocks: 64<-96,100  74<-104,108  84<-112,116  94<-120,124
        "v_mov_b32 v64, v96\n"   "v_mov_b32 v65, v100\n"
        "v_mov_b32 v66, v97\n"   "v_mov_b32 v67, v101\n"
        "v_mov_b32 v68, v98\n"   "v_mov_b32 v69, v102\n"
        "v_mov_b32 v70, v99\n"   "v_mov_b32 v71, v103\n"
        "v_mul_f32 v72, v96, v96\n"  "v_fmac_f32 v72, v97, v97\n"
        "v_fmac_f32 v72, v98, v98\n" "v_fmac_f32 v72, v99, v99\n"
        "v_mul_f32 v72, -0.5, v72\n"
        "v_mul_f32 v73, v100, v100\n" "v_fmac_f32 v73, v101, v101\n"
        "v_fmac_f32 v73, v102, v102\n" "v_fmac_f32 v73, v103, v103\n"
        "v_mul_f32 v73, -0.5, v73\n"
        "v_mov_b32 v74, v104\n"  "v_mov_b32 v75, v108\n"
        "v_mov_b32 v76, v105\n"  "v_mov_b32 v77, v109\n"
        "v_mov_b32 v78, v106\n"  "v_mov_b32 v79, v110\n"
        "v_mov_b32 v80, v107\n"  "v_mov_b32 v81, v111\n"
        "v_mul_f32 v82, v104, v104\n" "v_fmac_f32 v82, v105, v105\n"
        "v_fmac_f32 v82, v106, v106\n" "v_fmac_f32 v82, v107, v107\n"
        "v_mul_f32 v82, -0.5, v82\n"
        "v_mul_f32 v83, v108, v108\n" "v_fmac_f32 v83, v109, v109\n"
        "v_fmac_f32 v83, v110, v110\n" "v_fmac_f32 v83, v111, v111\n"
        "v_mul_f32 v83, -0.5, v83\n"
        "v_mov_b32 v84, v112\n"  "v_mov_b32 v85, v116\n"
        "v_mov_b32 v86, v113\n"  "v_mov_b32 v87, v117\n"
        "v_mov_b32 v88, v114\n"  "v_mov_b32 v89, v118\n"
        "v_mov_b32 v90, v115\n"  "v_mov_b32 v91, v119\n"
        "v_mul_f32 v92, v112, v112\n" "v_fmac_f32 v92, v113, v113\n"
        "v_fmac_f32 v92, v114, v114\n" "v_fmac_f32 v92, v115, v115\n"
        "v_mul_f32 v92, -0.5, v92\n"
        "v_mul_f32 v93, v116, v116\n" "v_fmac_f32 v93, v117, v117\n"
        "v_fmac_f32 v93, v118, v118\n" "v_fmac_f32 v93, v119, v119\n"
        "v_mul_f32 v93, -0.5, v93\n"
        "v_mov_b32 v94, v120\n"  "v_mov_b32 v95, v124\n"
        "v_mov_b32 v96, v121\n"  "v_mov_b32 v97, v125\n"
        "v_mov_b32 v98, v122\n"  "v_mov_b32 v99, v126\n"
        "v_mov_b32 v100, v123\n" "v_mov_b32 v101, v127\n"
        "v_mul_f32 v102, v120, v120\n" "v_fmac_f32 v102, v121, v121\n"
        "v_fmac_f32 v102, v122, v122\n" "v_fmac_f32 v102, v123, v123\n"
        "v_mul_f32 v102, -0.5, v102\n"
        "v_mul_f32 v103, v124, v124\n" "v_fmac_f32 v103, v125, v125\n"
        "v_fmac_f32 v103, v126, v126\n" "v_fmac_f32 v103, v127, v127\n"
        "v_mul_f32 v103, -0.5, v103\n"
        // ---- M addrs, M init to 0, loop counter ----
        "v_mov_b32 v126, %[mr]\n"
        "v_mov_b32 v127, %[mw]\n"
        "v_mov_b32 v116, 0\n" "v_mov_b32 v117, 0\n"
        "v_mov_b32 v118, 0\n" "v_mov_b32 v119, 0\n"
        "ds_write_b128 v127, v[116:119]\n"
        "s_movk_i32 s20, 63\n"
        // ================= forward recursion: 63 steps =================
        "L_fwd_%=:\n"
        "ds_read_b128 v[104:107], v22\n"
        "ds_read_b128 v[108:111], v22 offset:16\n"
        "ds_read2_b32 v[112:113], v126 offset0:0 offset1:64\n"
        "ds_read2_b32 v[114:115], v126 offset0:128 offset1:192\n"
        "s_waitcnt lgkmcnt(2)\n"
        // j=0 (into best), both P
        "v_pk_fma_f32 v[116:117], v[24:25], v[104:105], v[32:33]\n"
        "v_pk_fma_f32 v[118:119], v[64:65], v[104:105], v[72:73]\n"
        "v_pk_fma_f32 v[116:117], v[26:27], v[106:107], v[116:117]\n"
        "v_pk_fma_f32 v[118:119], v[66:67], v[106:107], v[118:119]\n"
        "v_pk_fma_f32 v[116:117], v[28:29], v[108:109], v[116:117]\n"
        "v_pk_fma_f32 v[118:119], v[68:69], v[108:109], v[118:119]\n"
        "v_pk_fma_f32 v[116:117], v[30:31], v[110:111], v[116:117]\n"
        "v_pk_fma_f32 v[118:119], v[70:71], v[110:111], v[118:119]\n"
        "s_waitcnt lgkmcnt(0)\n"
        "v_add_f32 v116, v112, v116\n"
        "v_add_f32 v117, v112, v117\n"
        "v_add_f32 v118, v112, v118\n"
        "v_add_f32 v119, v112, v119\n"
        // j=1 P0
        "v_pk_fma_f32 v[124:125], v[34:35], v[104:105], v[42:43]\n"
        "v_pk_fma_f32 v[124:125], v[36:37], v[106:107], v[124:125]\n"
        "v_pk_fma_f32 v[124:125], v[38:39], v[108:109], v[124:125]\n"
        "v_pk_fma_f32 v[124:125], v[40:41], v[110:111], v[124:125]\n"
        "v_add_f32 v124, v113, v124\n"
        "v_add_f32 v125, v113, v125\n"
        "v_cmp_gt_f32 vcc, v124, v116\n"
        "v_cndmask_b32 v120, 0, 1, vcc\n"
        "v_max_f32 v116, v116, v124\n"
        "v_cmp_gt_f32 vcc, v125, v117\n"
        "v_cndmask_b32 v121, 0, 1, vcc\n"
        "v_max_f32 v117, v117, v125\n"
        // j=1 P1
        "v_pk_fma_f32 v[124:125], v[74:75], v[104:105], v[82:83]\n"
        "v_pk_fma_f32 v[124:125], v[76:77], v[106:107], v[124:125]\n"
        "v_pk_fma_f32 v[124:125], v[78:79], v[108:109], v[124:125]\n"
        "v_pk_fma_f32 v[124:125], v[80:81], v[110:111], v[124:125]\n"
        "v_add_f32 v124, v113, v124\n"
        "v_add_f32 v125, v113, v125\n"
        "v_cmp_gt_f32 vcc, v124, v118\n"
        "v_cndmask_b32 v122, 0, 1, vcc\n"
        "v_max_f32 v118, v118, v124\n"
        "v_cmp_gt_f32 vcc, v125, v119\n"
        "v_cndmask_b32 v123, 0, 1, vcc\n"
        "v_max_f32 v119, v119, v125\n"
        // j=2 P0
        "v_pk_fma_f32 v[124:125], v[44:45], v[104:105], v[52:53]\n"
        "v_pk_fma_f32 v[124:125], v[46:47], v[106:107], v[124:125]\n"
        "v_pk_fma_f32 v[124:125], v[48:49], v[108:109], v[124:125]\n"
        "v_pk_fma_f32 v[124:125], v[50:51], v[110:111], v[124:125]\n"
        "v_add_f32 v124, v114, v124\n"
        "v_add_f32 v125, v114, v125\n"
        "v_cmp_gt_f32 vcc, v124, v116\n"
        "v_cndmask_b32 v120, v120, 2, vcc\n"
        "v_max_f32 v116, v116, v124\n"
        "v_cmp_gt_f32 vcc, v125, v117\n"
        "v_cndmask_b32 v121, v121, 2, vcc\n"
        "v_max_f32 v117, v117, v125\n"
        // j=2 P1
        "v_pk_fma_f32 v[124:125], v[84:85], v[104:105], v[92:93]\n"
        "v_pk_fma_f32 v[124:125], v[86:87], v[106:107], v[124:125]\n"
        "v_pk_fma_f32 v[124:125], v[88:89], v[108:109], v[124:125]\n"
        "v_pk_fma_f32 v[124:125], v[90:91], v[110:111], v[124:125]\n"
        "v_add_f32 v124, v114, v124\n"
        "v_add_f32 v125, v114, v125\n"
        "v_cmp_gt_f32 vcc, v124, v118\n"
        "v_cndmask_b32 v122, v122, 2, vcc\n"
        "v_max_f32 v118, v118, v124\n"
        "v_cmp_gt_f32 vcc, v125, v119\n"
        "v_cndmask_b32 v123, v123, 2, vcc\n"
        "v_max_f32 v119, v119, v125\n"
        // j=3 P0
        "v_pk_fma_f32 v[124:125], v[54:55], v[104:105], v[62:63]\n"
        "v_pk_fma_f32 v[124:125], v[56:57], v[106:107], v[124:125]\n"
        "v_pk_fma_f32 v[124:125], v[58:59], v[108:109], v[124:125]\n"
        "v_pk_fma_f32 v[124:125], v[60:61], v[110:111], v[124:125]\n"
        "v_add_f32 v124, v115, v124\n"
        "v_add_f32 v125, v115, v125\n"
        "v_cmp_gt_f32 vcc, v124, v116\n"
        "v_cndmask_b32 v120, v120, 3, vcc\n"
        "v_max_f32 v116, v116, v124\n"
        "v_cmp_gt_f32 vcc, v125, v117\n"
        "v_cndmask_b32 v121, v121, 3, vcc\n"
        "v_max_f32 v117, v117, v125\n"
        // j=3 P1
        "v_pk_fma_f32 v[124:125], v[94:95], v[104:105], v[102:103]\n"
        "v_pk_fma_f32 v[124:125], v[96:97], v[106:107], v[124:125]\n"
        "v_pk_fma_f32 v[124:125], v[98:99], v[108:109], v[124:125]\n"
        "v_pk_fma_f32 v[124:125], v[100:101], v[110:111], v[124:125]\n"
        "v_add_f32 v124, v115, v124\n"
        "v_add_f32 v125, v115, v125\n"
        "v_cmp_gt_f32 vcc, v124, v118\n"
        "v_cndmask_b32 v122, v122, 3, vcc\n"
        "v_max_f32 v118, v118, v124\n"
        "v_cmp_gt_f32 vcc, v125, v119\n"
        "v_cndmask_b32 v123, v123, 3, vcc\n"
        "v_max_f32 v119, v119, v125\n"
        // pack nib, store J + M, advance
        "v_lshlrev_b32 v124, 2, v121\n"
        "v_or_b32 v120, v120, v124\n"
        "v_lshlrev_b32 v124, 4, v122\n"
        "v_or_b32 v120, v120, v124\n"
        "v_lshlrev_b32 v124, 6, v123\n"
        "v_or_b32 v120, v120, v124\n"
        "ds_write_b128 v127, v[116:119]\n"
        "ds_write_b8 v23, v120\n"
        "v_add_u32 v22, 32, v22\n"
        "v_add_u32 v23, 64, v23\n"
        "s_waitcnt lgkmcnt(0)\n"
        "s_sub_u32 s20, s20, 1\n"
        "s_cmp_lg_u32 s20, 0\n"
        "s_cbranch_scc1 L_fwd_%=\n"
        :
        : [vt] "v"(t_off), [vj] "v"(j_off), [mr] "v"(mr_off),
          [mw] "v"(mw_off), [go] "v"(g_off), [cbp] "s"(cbook)
        : "memory", "vcc", "scc", "s20",
          "v22","v23","v24","v25","v26","v27","v28","v29","v30","v31",
          "v32","v33","v34","v35","v36","v37","v38","v39","v40","v41",
          "v42","v43","v44","v45","v46","v47","v48","v49","v50","v51",
          "v52","v53","v54","v55","v56","v57","v58","v59","v60","v61",
          "v62","v63","v64","v65","v66","v67","v68","v69","v70","v71",
          "v72","v73","v74","v75","v76","v77","v78","v79","v80","v81",
          "v82","v83","v84","v85","v86","v87","v88","v89","v90","v91",
          "v92","v93","v94","v95","v96","v97","v98","v99","v100","v101",
          "v102","v103","v104","v105","v106","v107","v108","v109","v110","v111",
          "v112","v113","v114","v115","v116","v117","v118","v119","v120","v121",
          "v122","v123","v124","v125","v126","v127");

    // ---- final step t = 63: full argmax over beta_63[0..1023] (C++) ----
    int bests;
    {
        const float x0 = tile2[504], y0 = tile2[506],
                    z0 = tile2[508], w0 = tile2[510];
        float mj[4];
        #pragma unroll
        for (int j = 0; j < 4; ++j) mj[j] = Msh[lane + 64 * j];

        float bv = -3.4e38f;
        int   bs = 0;
        #pragma unroll
        for (int j = 0; j < 4; ++j) {      // s = 4L+c+256j: ascending (j,c)
            #pragma unroll
            for (int c = 0; c < 4; ++c) {
                const int row = 4 * lane + c + (j << 8);
                float4 v = *(const float4*)(cbook + row * 4);
                float h = -0.5f * (v.x * v.x + v.y * v.y +
                                   v.z * v.z + v.w * v.w);
                float acc = fmaf(v.x, x0, h);
                acc = fmaf(v.y, y0, acc);
                acc = fmaf(v.z, z0, acc);
                acc = fmaf(v.w, w0, acc);
                acc += mj[j];
                if (acc > bv) { bv = acc; bs = row; }
            }
        }
        #pragma unroll
        for (int off = 32; off > 0; off >>= 1) {
            const float ov = __shfl_xor(bv, off, 64);
            const int   os = __shfl_xor(bs, off, 64);
            if (ov > bv || (ov == bv && os < bs)) { bv = ov; bs = os; }
        }
        bests = bs;
    }

    // ---- traceback (serial, lane 0) ----
    if (lane == 0) {
        int s = bests;
        st_lds[T_STEPS - 1] = s;
        for (int i = T_STEPS - 2; i >= 0; --i) {
            const int p = s >> 2;
            const unsigned byte = Jsh[i * 64 + (p >> 2)];
            const int j = (byte >> (2 * (p & 3))) & 3;
            s = p + (j << 8);
            st_lds[i] = s;
        }
    }
    __syncthreads();

    // ---- outputs ----
    const int st = st_lds[lane];
    out[REC_SIZE + chain * 64 + lane] = (float)st;   // states (as float)
    const float4 v = *(const float4*)(cbook + st * 4);
    const int r  = lane >> 2;
    const int c4 = (lane & 3) << 2;
    *(float4*)(out + (rb * 16 + r) * COLS + cbc * 16 + c4) = v;
}

extern "C" void kernel_launch(void* const* d_in, const int* in_sizes, int n_in,
                              void* d_out, int out_size, void* d_ws, size_t ws_size,
                              hipStream_t stream)
{
    const float* arr   = (const float*)d_in[0];
    const float* cbook = (const float*)d_in[1];
    float* out = (float*)d_out;
    // one chain per 64-thread block (1 wave/chain), 4096 blocks
    viterbi_q<<<dim3(4096), dim3(64), 0, stream>>>(arr, cbook, out);
}